// Round 14
// baseline (188.416 us; speedup 1.0000x reference)
//
#include <hip/hip_runtime.h>

#define TT 4096
#define DIN 1024

typedef _Float16 f16;
typedef __attribute__((ext_vector_type(8))) _Float16 f16x8;
typedef __attribute__((ext_vector_type(4))) _Float16 f16x4;
typedef __attribute__((ext_vector_type(4))) float f32x4;

// ---- device-global scratch ----
__device__ f16 g_xh[TT * DIN];               // x cast to f16            8 MB
__device__ f16 g_wqkvT[3 * DIN * DIN];       // [Wq^T|Wk^T|Wv^T] f16     6 MB
__device__ f16 g_wrT[DIN * DIN];             // Wr^T f16                 2 MB
__device__ f16 g_q[TT * DIN];                // q (+bias)                8 MB
__device__ f16 g_k[TT * DIN];                // k (+bias)                8 MB
__device__ f16 g_v[TT * DIN];                // v row-major (+bias)      8 MB
__device__ f16 g_vT[DIN * TT];               // v transposed             8 MB
__device__ f16 g_sg[(size_t)TT * TT];        // S, then gamma.*S        32 MB
__device__ f16 g_part[4][TT * DIN];          // split-K partials f16    32 MB
__device__ f16 g_ret[TT * DIN];              // retained                 8 MB

// ---- prep kernels ----
__global__ __launch_bounds__(256) void prep_cast_x(const float* __restrict__ x) {
    int i = (blockIdx.x * 256 + threadIdx.x) * 8;
    f32x4 a = *(const f32x4*)&x[i];
    f32x4 b = *(const f32x4*)&x[i + 4];
    f16x8 o;
#pragma unroll
    for (int j = 0; j < 4; ++j) { o[j] = (f16)a[j]; o[j + 4] = (f16)b[j]; }
    *(f16x8*)&g_xh[i] = o;
}

// LDS-tiled transpose-cast, coalesced both sides (r8, validated)
__global__ __launch_bounds__(256) void prep_transpose(const float* __restrict__ Wq,
                                                      const float* __restrict__ Wk,
                                                      const float* __restrict__ Wv,
                                                      const float* __restrict__ Wr) {
    __shared__ float tt[64][68];
    const int which = blockIdx.z;
    const float* src = (which == 0) ? Wq : (which == 1) ? Wk : (which == 2) ? Wv : Wr;
    f16* dst = (which < 3) ? (g_wqkvT + (size_t)which * DIN * DIN) : g_wrT;
    const int t = threadIdx.x;
    const int r = t >> 2;
    const int c0 = (t & 3) * 4;
#pragma unroll
    for (int ch = 0; ch < 4; ++ch)
        *(f32x4*)&tt[r][c0 + ch * 16] =
            *(const f32x4*)&src[(size_t)(blockIdx.y * 64 + r) * DIN + blockIdx.x * 64 + c0 + ch * 16];
    __syncthreads();
#pragma unroll
    for (int p = 0; p < 2; ++p) {
        const int j  = (t >> 3) + p * 32;
        const int k0 = (t & 7) * 8;
        f16x8 o;
#pragma unroll
        for (int jj = 0; jj < 8; ++jj) o[jj] = (f16)tt[k0 + jj][j];
        *(f16x8*)&dst[(size_t)(blockIdx.x * 64 + j) * DIN + blockIdx.y * 64 + k0] = o;
    }
}

// LDS-tiled transpose: g_v [4096][1024] -> g_vT [1024][4096]
__global__ __launch_bounds__(256) void transpose_v() {
    __shared__ f16 t[64][72];
    const int bc = blockIdx.x;
    const int br = blockIdx.y;
    const int tdx = threadIdx.x;
    const int r0 = tdx >> 3;
    const int c8 = (tdx & 7) * 8;
#pragma unroll
    for (int p = 0; p < 2; ++p) {
        int r = r0 + p * 32;
        *(f16x8*)&t[r][c8] = *(const f16x8*)&g_v[(size_t)(br * 64 + r) * DIN + bc * 64 + c8];
    }
    __syncthreads();
#pragma unroll
    for (int p = 0; p < 2; ++p) {
        int c = r0 + p * 32;
        f16x8 v;
#pragma unroll
        for (int j = 0; j < 8; ++j) v[j] = t[c8 + j][c];
        *(f16x8*)&g_vT[(size_t)(bc * 64 + c) * TT + br * 64 + c8] = v;
    }
}

// streaming elementwise: g_sg = (f16)(g_sg * gamma), in-place, 32 waves/CU
__global__ __launch_bounds__(256) void gamma_mult(const float* __restrict__ gamma) {
    const size_t total = (size_t)TT * TT;
    const size_t stride = (size_t)gridDim.x * 256 * 8;
    for (size_t i = ((size_t)blockIdx.x * 256 + threadIdx.x) * 8; i < total; i += stride) {
        f16x8 sv = *(const f16x8*)&g_sg[i];
        f32x4 g0 = *(const f32x4*)&gamma[i];
        f32x4 g1 = *(const f32x4*)&gamma[i + 4];
        f16x8 o;
#pragma unroll
        for (int j = 0; j < 4; ++j) {
            o[j]     = (f16)((float)sv[j] * g0[j]);
            o[j + 4] = (f16)((float)sv[j + 4] * g1[j]);
        }
        *(f16x8*)&g_sg[i] = o;
    }
}

// ---- async global->LDS, 16B per lane, wave-uniform LDS base ----
__device__ __forceinline__ void gload_lds16(const void* g, void* l) {
    __builtin_amdgcn_global_load_lds(
        (const __attribute__((address_space(1))) unsigned int*)g,
        (__attribute__((address_space(3))) unsigned int*)l,
        16, 0, 0);
}

// ================= 256x256 8-phase GEMM, C = A * B^T =================
// r8-EXACT K-loop (no per-phase lgkmcnt fence — r13 showed that fence costs
// ~11us total: compiler already emits fine-grained lgkmcnt(4/3/1) for the
// ds_read->MFMA deps; blanket lgkmcnt(0)+sched_barrier(0) serializes phases).
// BK=64, 8 waves (2Mx4N), LDS 2 tile-buffers x 64KB.
// Swizzle byte ^= (row&7)<<4 on stage SOURCE col and ds_read col.
// vmcnt ledger: steady kt outstanding = B(kt)4 + A(kt)4 + B(kt+1)4 = 12 ->
// vmcnt(4); last kt full drain vmcnt(0) (r3 race fix).
// A(kt+1) -> other buffer (GPHASE 0/2); B(kt+2) -> current buffer (GPHASE 4/6).
//
// Epilogue: per-wave LDS micro-repack -> packed f16x8 stores (r7, validated).
// EPI 0: -> q|k|v (+bias), select by bx>>2, all row-major.
// EPI 1: -> g_sg = PURE S (gamma applied by gamma_mult; r7-measured best split).
// EPI 2: -> g_part[z], split-K z over K=4096/4.
// EPI 3: -> g_part[z], split-K z over K=1024/4 (NT=4).
template <int EPI>
__global__ __launch_bounds__(512, 2) void gemm8(const float* __restrict__ bq,
                                                const float* __restrict__ bk,
                                                const float* __restrict__ bv) {
    constexpr int NT  = (EPI == 3) ? 4 : 16;         // K-tiles of 64
    constexpr int ld2A = (EPI == 2) ? 8192 : 2048;   // A row bytes
    constexpr int ld2B = (EPI == 2) ? 8192 : 2048;   // B row bytes

    const f16* Ap = (EPI == 0) ? g_xh : (EPI == 1) ? g_q : (EPI == 2) ? g_sg : g_ret;
    const f16* Bp = (EPI == 0) ? g_wqkvT : (EPI == 1) ? g_k : (EPI == 2) ? g_vT : g_wrT;
    const int kb_base = (EPI == 2) ? blockIdx.z * 2048
                      : (EPI == 3) ? blockIdx.z * 512 : 0;   // byte offset of K-slice

    __shared__ __align__(16) char smem[131072];

    const int t = threadIdx.x;
    const int w = t >> 6, l = t & 63;
    const int wr = w >> 2, wc = w & 3;               // 2M x 4N waves
    const int fr = l & 15;
    const int fkb = (l >> 4) * 16;                   // fragment k-byte (0..48)

    // XCD swizzle over (x,y) (bijective: all grids have nwg%8==0)
    const int nx = gridDim.x;
    const int lin = blockIdx.y * nx + blockIdx.x;
    const int cpx = (nx * gridDim.y) >> 3;
    const int sw = (lin & 7) * cpx + (lin >> 3);
    const int bx = sw % nx, by = sw / nx;
    const int arow0 = by * 256;
    const int bcol0 = bx * 256;

    auto stage = [&](const f16* M, int ld2, int row0, int kb0, int dstoff) {
#pragma unroll
        for (int r = 0; r < 2; ++r) {
            int off = r * 8192 + w * 1024;           // wave-uniform LDS offset
            int row = (off + l * 16) >> 7;
            int scb = ((l & 7) * 16) ^ ((row & 7) << 4);   // inverse-swizzle SOURCE
            const char* src = (const char*)M + (size_t)(row0 + row) * ld2 + kb0 + scb;
            gload_lds16(src, smem + dstoff + off);
        }
    };

    auto ldsA = [&](int c, int m, int ks) -> f16x8 {
        int lr = m * 16 + fr;
        int kb = ks * 64 + fkb;
        return *(const f16x8*)(smem + c * 65536 + wr * 16384 + lr * 128 + (kb ^ ((lr & 7) << 4)));
    };
    auto ldsB = [&](int c, int n, int ks) -> f16x8 {
        int lc = (wc & 1) * 64 + n * 16 + fr;
        int kb = ks * 64 + fkb;
        return *(const f16x8*)(smem + c * 65536 + 32768 + (wc >> 1) * 16384 + lc * 128 + (kb ^ ((lc & 7) << 4)));
    };

#define KB(kt) (kb_base + (kt) * 128)

    // prologue: tile0 complete + tile1 B-halves (12 loads/thread in flight)
    stage(Ap, ld2A, arow0,       KB(0), 0);
    stage(Ap, ld2A, arow0 + 128, KB(0), 16384);
    stage(Bp, ld2B, bcol0,       KB(0), 32768);
    stage(Bp, ld2B, bcol0 + 128, KB(0), 49152);
    stage(Bp, ld2B, bcol0,       KB(1), 65536 + 32768);
    stage(Bp, ld2B, bcol0 + 128, KB(1), 65536 + 49152);

    f32x4 acc[8][4] = {};
    f16x8 bf[4][2];

#define GPHASE(MB, STAGE_STMT)                                              \
    {                                                                       \
        f16x8 af[2][2];                                                     \
        _Pragma("unroll") for (int i = 0; i < 2; ++i)                       \
            _Pragma("unroll") for (int ks = 0; ks < 2; ++ks)                \
                af[i][ks] = ldsA(c, (MB) + i, ks);                          \
        STAGE_STMT;                                                         \
        __builtin_amdgcn_s_barrier();                                       \
        __builtin_amdgcn_s_setprio(1);                                      \
        _Pragma("unroll") for (int i = 0; i < 2; ++i)                       \
            _Pragma("unroll") for (int n = 0; n < 4; ++n)                   \
                _Pragma("unroll") for (int ks = 0; ks < 2; ++ks)            \
                    acc[(MB) + i][n] = __builtin_amdgcn_mfma_f32_16x16x32_f16( \
                        af[i][ks], bf[n][ks], acc[(MB) + i][n], 0, 0, 0);   \
        __builtin_amdgcn_s_setprio(0);                                      \
        __builtin_amdgcn_s_barrier();                                       \
    }

    for (int kt = 0; kt < NT; ++kt) {
        const int c = kt & 1;
        if (kt == NT - 1) asm volatile("s_waitcnt vmcnt(0)" ::: "memory");
        else              asm volatile("s_waitcnt vmcnt(4)" ::: "memory");
        __builtin_amdgcn_s_barrier();
#pragma unroll
        for (int n = 0; n < 4; ++n)
#pragma unroll
            for (int ks = 0; ks < 2; ++ks) bf[n][ks] = ldsB(c, n, ks);
        GPHASE(0, if (kt + 1 < NT) stage(Ap, ld2A, arow0,       KB(kt + 1), (c ^ 1) * 65536))
        GPHASE(2, if (kt + 1 < NT) stage(Ap, ld2A, arow0 + 128, KB(kt + 1), (c ^ 1) * 65536 + 16384))
        GPHASE(4, if (kt + 2 < NT) stage(Bp, ld2B, bcol0,       KB(kt + 2), c * 65536 + 32768))
        GPHASE(6, if (kt + 2 < NT) stage(Bp, ld2B, bcol0 + 128, KB(kt + 2), c * 65536 + 49152))
    }
#undef GPHASE
#undef KB

    // ------------- per-wave LDS micro-repack epilogue -------------
    __syncthreads();                                 // K-loop LDS fully retired
    char* slice = smem + w * 16384;                  // wave-private f16[128][64]
    const int rb = (l >> 4) * 4;
    const int crow0 = arow0 + wr * 128;
    const int ccol0 = bcol0 + wc * 64;

    const int sel = (EPI == 0) ? (bx >> 2) : 0;      // 0=q 1=k 2=v
    const float* bias0 = (EPI == 0) ? ((sel == 0) ? bq : (sel == 1) ? bk : bv) : nullptr;
    const int cb0 = (EPI == 0) ? (ccol0 - sel * 1024) : ccol0;

    // phase 1: acc (+bias) -> f16 into swizzled wave slice
#pragma unroll
    for (int m = 0; m < 8; ++m)
#pragma unroll
        for (int n = 0; n < 4; ++n) {
            float bsum = 0.f;
            if constexpr (EPI == 0) bsum = bias0[cb0 + n * 16 + fr];
#pragma unroll
            for (int j = 0; j < 4; ++j) {
                const int lr = m * 16 + rb + j;
                const int lcb = (n * 16 + fr) * 2;
                *(f16*)(slice + lr * 128 + (lcb ^ ((lr & 7) << 4))) = (f16)(acc[m][n][j] + bsum);
            }
        }
    asm volatile("s_waitcnt lgkmcnt(0)" ::: "memory");   // wave-internal writes visible
    __builtin_amdgcn_sched_barrier(0);                    // rule 18: pin reads after wait

    // phase 2: packed coalesced stores (16B/lane, 8x128B segments/inst)
    f16* dst;
    int ld;
    if constexpr (EPI == 0)      { dst = (sel == 0) ? g_q : (sel == 1) ? g_k : g_v; ld = 1024; }
    else if constexpr (EPI == 1) { dst = g_sg;               ld = TT;   }
    else                         { dst = g_part[blockIdx.z]; ld = 1024; }
#pragma unroll
    for (int i = 0; i < 16; ++i) {
        const int r  = i * 8 + (l >> 3);
        const int cb = (l & 7) * 16;
        f16x8 vv = *(const f16x8*)(slice + r * 128 + (cb ^ ((r & 7) << 4)));
        *(f16x8*)&dst[(size_t)(crow0 + r) * ld + cb0 + (l & 7) * 8] = vv;
    }
}

// sum 4 split-K f16 partials -> g_ret f16
__global__ __launch_bounds__(256) void reduce_parts() {
    size_t i = (size_t)(blockIdx.x * 256 + threadIdx.x) * 8;
    f16x8 a = *(const f16x8*)&g_part[0][i];
    f16x8 b = *(const f16x8*)&g_part[1][i];
    f16x8 cc = *(const f16x8*)&g_part[2][i];
    f16x8 d = *(const f16x8*)&g_part[3][i];
    f16x8 o;
#pragma unroll
    for (int j = 0; j < 8; ++j)
        o[j] = (f16)((float)a[j] + (float)b[j] + (float)cc[j] + (float)d[j]);
    *(f16x8*)&g_ret[i] = o;
}

// sum 4 split-K f16 partials + bias + PReLU -> out f32
__global__ __launch_bounds__(256) void reduce_out(const float* __restrict__ br,
                                                  const float* __restrict__ prelu_a,
                                                  float* __restrict__ out) {
    size_t i = (size_t)(blockIdx.x * 256 + threadIdx.x) * 8;
    f16x8 a = *(const f16x8*)&g_part[0][i];
    f16x8 b = *(const f16x8*)&g_part[1][i];
    f16x8 cc = *(const f16x8*)&g_part[2][i];
    f16x8 d = *(const f16x8*)&g_part[3][i];
    const float pa = *prelu_a;
    const int col = (int)(i & 1023);
    const f32x4 b0 = *(const f32x4*)&br[col];
    const f32x4 b1 = *(const f32x4*)&br[col + 4];
    f32x4 o0, o1;
#pragma unroll
    for (int j = 0; j < 4; ++j) {
        float s = (float)a[j] + (float)b[j] + (float)cc[j] + (float)d[j] + b0[j];
        o0[j] = (s >= 0.f) ? s : pa * s;
    }
#pragma unroll
    for (int j = 0; j < 4; ++j) {
        float s = (float)a[j + 4] + (float)b[j + 4] + (float)cc[j + 4] + (float)d[j + 4] + b1[j];
        o1[j] = (s >= 0.f) ? s : pa * s;
    }
    *(f32x4*)&out[i] = o0;
    *(f32x4*)&out[i + 4] = o1;
}

extern "C" void kernel_launch(void* const* d_in, const int* in_sizes, int n_in,
                              void* d_out, int out_size, void* d_ws, size_t ws_size,
                              hipStream_t stream) {
    const float* x     = (const float*)d_in[0];
    const float* gamma = (const float*)d_in[1];
    const float* Wq    = (const float*)d_in[2];
    const float* bq    = (const float*)d_in[3];
    const float* Wk    = (const float*)d_in[4];
    const float* bk    = (const float*)d_in[5];
    const float* Wv    = (const float*)d_in[6];
    const float* bv    = (const float*)d_in[7];
    const float* Wr    = (const float*)d_in[8];
    const float* br    = (const float*)d_in[9];
    const float* pa    = (const float*)d_in[10];
    float* out = (float*)d_out;

    prep_cast_x<<<TT * DIN / 8 / 256, 256, 0, stream>>>(x);
    prep_transpose<<<dim3(16, 16, 4), 256, 0, stream>>>(Wq, Wk, Wv, Wr);

    // qkv  M=4096 N=3072 (192 blocks)
    gemm8<0><<<dim3(12, 16), 512, 0, stream>>>(bq, bk, bv);
    transpose_v<<<dim3(16, 64), 256, 0, stream>>>();
    // S = q k^T  M=4096 N=4096 (256 blocks)
    gemm8<1><<<dim3(16, 16), 512, 0, stream>>>(bq, bk, bv);
    // streaming gamma multiply (in-place on g_sg)
    gamma_mult<<<2048, 256, 0, stream>>>(gamma);
    // retained partials, split-K=4 over K=4096 (256 blocks)
    gemm8<2><<<dim3(4, 16, 4), 512, 0, stream>>>(bq, bk, bv);
    reduce_parts<<<TT * DIN / 8 / 256, 256, 0, stream>>>();
    // out partials, split-K=4 over K=1024 (NT=4, 256 blocks)
    gemm8<3><<<dim3(4, 16, 4), 512, 0, stream>>>(bq, bk, bv);
    reduce_out<<<TT * DIN / 8 / 256, 256, 0, stream>>>(br, pa, out);
}

// Round 15
// 176.912 us; speedup vs baseline: 1.0650x; 1.0650x over previous
//
#include <hip/hip_runtime.h>

#define TT 4096
#define DIN 1024

typedef _Float16 f16;
typedef __attribute__((ext_vector_type(8))) _Float16 f16x8;
typedef __attribute__((ext_vector_type(4))) _Float16 f16x4;
typedef __attribute__((ext_vector_type(4))) float f32x4;

// ---- device-global scratch ----
__device__ f16 g_xh[TT * DIN];               // x cast to f16            8 MB
__device__ f16 g_wqkvT[3 * DIN * DIN];       // [Wq^T|Wk^T|Wv^T] f16     6 MB
__device__ f16 g_wrT[DIN * DIN];             // Wr^T f16                 2 MB
__device__ f16 g_q[TT * DIN];                // q                        8 MB
__device__ f16 g_k[TT * DIN];                // k                        8 MB
__device__ f16 g_v[TT * DIN];                // v row-major              8 MB
__device__ f16 g_vT[DIN * TT];               // v transposed             8 MB
__device__ f16 g_sg[(size_t)TT * TT];        // gamma .* (q k^T)        32 MB
__device__ f16 g_part[4][TT * DIN];          // split-K partials f16    32 MB
__device__ f16 g_ret[TT * DIN];              // retained                 8 MB

// ---- prep kernels ----
__global__ __launch_bounds__(256) void prep_cast_x(const float* __restrict__ x) {
    int i = (blockIdx.x * 256 + threadIdx.x) * 8;
    f32x4 a = *(const f32x4*)&x[i];
    f32x4 b = *(const f32x4*)&x[i + 4];
    f16x8 o;
#pragma unroll
    for (int j = 0; j < 4; ++j) { o[j] = (f16)a[j]; o[j + 4] = (f16)b[j]; }
    *(f16x8*)&g_xh[i] = o;
}

// LDS-tiled transpose-cast: dst[j][k] = (f16)src[k][j], 64x64 f32 tiles.
__global__ __launch_bounds__(256) void prep_transpose(const float* __restrict__ Wq,
                                                      const float* __restrict__ Wk,
                                                      const float* __restrict__ Wv,
                                                      const float* __restrict__ Wr) {
    __shared__ float tt[64][68];                     // 272B rows: 16B-aligned
    const int which = blockIdx.z;
    const float* src = (which == 0) ? Wq : (which == 1) ? Wk : (which == 2) ? Wv : Wr;
    f16* dst = (which < 3) ? (g_wqkvT + (size_t)which * DIN * DIN) : g_wrT;
    const int t = threadIdx.x;
    const int r = t >> 2;                            // 0..63
    const int c0 = (t & 3) * 4;
#pragma unroll
    for (int ch = 0; ch < 4; ++ch)
        *(f32x4*)&tt[r][c0 + ch * 16] =
            *(const f32x4*)&src[(size_t)(blockIdx.y * 64 + r) * DIN + blockIdx.x * 64 + c0 + ch * 16];
    __syncthreads();
#pragma unroll
    for (int p = 0; p < 2; ++p) {
        const int j  = (t >> 3) + p * 32;            // dst row (= src col)
        const int k0 = (t & 7) * 8;
        f16x8 o;
#pragma unroll
        for (int jj = 0; jj < 8; ++jj) o[jj] = (f16)tt[k0 + jj][j];
        *(f16x8*)&dst[(size_t)(blockIdx.x * 64 + j) * DIN + blockIdx.y * 64 + k0] = o;
    }
}

// LDS-tiled transpose: g_v [4096][1024] -> g_vT [1024][4096]
__global__ __launch_bounds__(256) void transpose_v() {
    __shared__ f16 t[64][72];
    const int bc = blockIdx.x;
    const int br = blockIdx.y;
    const int tdx = threadIdx.x;
    const int r0 = tdx >> 3;
    const int c8 = (tdx & 7) * 8;
#pragma unroll
    for (int p = 0; p < 2; ++p) {
        int r = r0 + p * 32;
        *(f16x8*)&t[r][c8] = *(const f16x8*)&g_v[(size_t)(br * 64 + r) * DIN + bc * 64 + c8];
    }
    __syncthreads();
#pragma unroll
    for (int p = 0; p < 2; ++p) {
        int c = r0 + p * 32;
        f16x8 v;
#pragma unroll
        for (int j = 0; j < 8; ++j) v[j] = t[c8 + j][c];
        *(f16x8*)&g_vT[(size_t)(bc * 64 + c) * TT + br * 64 + c8] = v;
    }
}

// ---- async global->LDS, 16B per lane, wave-uniform LDS base ----
__device__ __forceinline__ void gload_lds16(const void* g, void* l) {
    __builtin_amdgcn_global_load_lds(
        (const __attribute__((address_space(1))) unsigned int*)g,
        (__attribute__((address_space(3))) unsigned int*)l,
        16, 0, 0);
}

// ================= 256x256 8-phase GEMM, C = A * B^T =================
// BK=64, 8 waves (2Mx4N), per-wave 128x64 out. LDS: 2 tile-buffers x 64KB.
// Swizzle: byte ^= (row&7)<<4 on stage SOURCE col and ds_read col.
// vmcnt ledger: steady kt outstanding = B(kt)4 + A(kt)4 + B(kt+1)4 = 12 ->
// vmcnt(4). Last kt: full drain vmcnt(0) (race fix, r3).
//
// Epilogue: per-wave LDS micro-repack -> packed f16x8 stores (r7, validated).
// EPI 0: -> q|k|v f16 (+bias), select by bx>>2
// EPI 1: -> g_sg = gamma .* S ; gamma fused in store phase: full-line f32x4
//         pair loads batched 8-iters deep (latency-hidden), then mul+store.
//         [r8=177.2us vs split gamma_mult=188us — fused is the measured best]
// EPI 2: -> g_part[z] f16, split-K over blockIdx.z (K=4096/4)
// EPI 3: -> g_part[z] f16, split-K over blockIdx.z (K=1024/4, NT=4)
template <int EPI>
__global__ __launch_bounds__(512, 2) void gemm8(const float* __restrict__ gamma,
                                                const float* __restrict__ bq,
                                                const float* __restrict__ bk,
                                                const float* __restrict__ bv) {
    constexpr int NT  = (EPI == 3) ? 4 : 16;         // K-tiles of 64
    constexpr int ld2A = (EPI == 2) ? 8192 : 2048;   // A row bytes
    constexpr int ld2B = (EPI == 2) ? 8192 : 2048;   // B row bytes

    const f16* Ap = (EPI == 0) ? g_xh : (EPI == 1) ? g_q : (EPI == 2) ? g_sg : g_ret;
    const f16* Bp = (EPI == 0) ? g_wqkvT : (EPI == 1) ? g_k : (EPI == 2) ? g_vT : g_wrT;
    const int kb_base = (EPI == 2) ? blockIdx.z * 2048
                      : (EPI == 3) ? blockIdx.z * 512 : 0;   // byte offset of K-slice

    __shared__ __align__(16) char smem[131072];

    const int t = threadIdx.x;
    const int w = t >> 6, l = t & 63;
    const int wr = w >> 2, wc = w & 3;               // 2M x 4N waves
    const int fr = l & 15;
    const int fkb = (l >> 4) * 16;                   // fragment k-byte (0..48)

    // XCD swizzle over (x,y) (bijective: all grids have nwg%8==0)
    const int nx = gridDim.x;
    const int lin = blockIdx.y * nx + blockIdx.x;
    const int cpx = (nx * gridDim.y) >> 3;
    const int sw = (lin & 7) * cpx + (lin >> 3);
    const int bx = sw % nx, by = sw / nx;
    const int arow0 = by * 256;
    const int bcol0 = bx * 256;

    auto stage = [&](const f16* M, int ld2, int row0, int kb0, int dstoff) {
#pragma unroll
        for (int r = 0; r < 2; ++r) {
            int off = r * 8192 + w * 1024;           // wave-uniform LDS offset
            int row = (off + l * 16) >> 7;
            int cb  = (l & 7) * 16;
            int scb = cb ^ ((row & 7) << 4);         // inverse-swizzle the SOURCE
            const char* src = (const char*)M + (size_t)(row0 + row) * ld2 + kb0 + scb;
            gload_lds16(src, smem + dstoff + off);
        }
    };

    auto ldsA = [&](int c, int m, int ks) -> f16x8 {
        int lr = m * 16 + fr;
        int kb = ks * 64 + fkb;
        return *(const f16x8*)(smem + c * 65536 + wr * 16384 + lr * 128 + (kb ^ ((lr & 7) << 4)));
    };
    auto ldsB = [&](int c, int n, int ks) -> f16x8 {
        int lc = (wc & 1) * 64 + n * 16 + fr;
        int kb = ks * 64 + fkb;
        return *(const f16x8*)(smem + c * 65536 + 32768 + (wc >> 1) * 16384 + lc * 128 + (kb ^ ((lc & 7) << 4)));
    };

#define KB(kt) (kb_base + (kt) * 128)

    // prologue: tile0 complete + tile1 B-halves (12 loads/thread in flight)
    stage(Ap, ld2A, arow0,       KB(0), 0);
    stage(Ap, ld2A, arow0 + 128, KB(0), 16384);
    stage(Bp, ld2B, bcol0,       KB(0), 32768);
    stage(Bp, ld2B, bcol0 + 128, KB(0), 49152);
    stage(Bp, ld2B, bcol0,       KB(1), 65536 + 32768);
    stage(Bp, ld2B, bcol0 + 128, KB(1), 65536 + 49152);

    f32x4 acc[8][4] = {};
    f16x8 bf[4][2];

#define GPHASE(MB, STAGE_STMT)                                              \
    {                                                                       \
        f16x8 af[2][2];                                                     \
        _Pragma("unroll") for (int i = 0; i < 2; ++i)                       \
            _Pragma("unroll") for (int ks = 0; ks < 2; ++ks)                \
                af[i][ks] = ldsA(c, (MB) + i, ks);                          \
        STAGE_STMT;                                                         \
        __builtin_amdgcn_s_barrier();                                       \
        __builtin_amdgcn_s_setprio(1);                                      \
        _Pragma("unroll") for (int i = 0; i < 2; ++i)                       \
            _Pragma("unroll") for (int n = 0; n < 4; ++n)                   \
                _Pragma("unroll") for (int ks = 0; ks < 2; ++ks)            \
                    acc[(MB) + i][n] = __builtin_amdgcn_mfma_f32_16x16x32_f16( \
                        af[i][ks], bf[n][ks], acc[(MB) + i][n], 0, 0, 0);   \
        __builtin_amdgcn_s_setprio(0);                                      \
        __builtin_amdgcn_s_barrier();                                       \
    }

    for (int kt = 0; kt < NT; ++kt) {
        const int c = kt & 1;
        if (kt == NT - 1) asm volatile("s_waitcnt vmcnt(0)" ::: "memory");
        else              asm volatile("s_waitcnt vmcnt(4)" ::: "memory");
        __builtin_amdgcn_s_barrier();
#pragma unroll
        for (int n = 0; n < 4; ++n)
#pragma unroll
            for (int ks = 0; ks < 2; ++ks) bf[n][ks] = ldsB(c, n, ks);
        GPHASE(0, if (kt + 1 < NT) stage(Ap, ld2A, arow0,       KB(kt + 1), (c ^ 1) * 65536))
        GPHASE(2, if (kt + 1 < NT) stage(Ap, ld2A, arow0 + 128, KB(kt + 1), (c ^ 1) * 65536 + 16384))
        GPHASE(4, if (kt + 2 < NT) stage(Bp, ld2B, bcol0,       KB(kt + 2), c * 65536 + 32768))
        GPHASE(6, if (kt + 2 < NT) stage(Bp, ld2B, bcol0 + 128, KB(kt + 2), c * 65536 + 49152))
    }
#undef GPHASE
#undef KB

    // ------------- per-wave LDS micro-repack epilogue -------------
    __syncthreads();                                 // K-loop LDS fully retired
    char* slice = smem + w * 16384;                  // wave-private f16[128][64]
    const int rb = (l >> 4) * 4;
    const int crow0 = arow0 + wr * 128;
    const int ccol0 = bcol0 + wc * 64;

    const int sel = (EPI == 0) ? (bx >> 2) : 0;      // 0=q 1=k 2=v
    const float* bias0 = (EPI == 0) ? ((sel == 0) ? bq : (sel == 1) ? bk : bv) : nullptr;
    const int cb0 = (EPI == 0) ? (ccol0 - sel * 1024) : ccol0;

    // phase 1: acc (+bias) -> f16 into swizzled wave slice
#pragma unroll
    for (int m = 0; m < 8; ++m)
#pragma unroll
        for (int n = 0; n < 4; ++n) {
            float bsum = 0.f;
            if constexpr (EPI == 0) bsum = bias0[cb0 + n * 16 + fr];
#pragma unroll
            for (int j = 0; j < 4; ++j) {
                const int lr = m * 16 + rb + j;
                const int lcb = (n * 16 + fr) * 2;
                *(f16*)(slice + lr * 128 + (lcb ^ ((lr & 7) << 4))) = (f16)(acc[m][n][j] + bsum);
            }
        }
    asm volatile("s_waitcnt lgkmcnt(0)" ::: "memory");   // wave-internal writes visible
    __builtin_amdgcn_sched_barrier(0);                    // rule 18: pin reads after wait

    // phase 2: packed coalesced stores (16B/lane, 8x128B segments/inst)
    if constexpr (EPI == 1) {
        // gamma fused: two groups of 8 iters; batch-issue 16 f32x4 gamma loads
        // per group (latency-hidden), then ds_read + mul + packed store.
#pragma unroll 1
        for (int g = 0; g < 2; ++g) {
            f32x4 ga[8][2];
#pragma unroll
            for (int i = 0; i < 8; ++i) {
                const int r = (g * 8 + i) * 8 + (l >> 3);
                const float* gp = &gamma[(size_t)(crow0 + r) * TT + ccol0 + (l & 7) * 8];
                ga[i][0] = *(const f32x4*)gp;
                ga[i][1] = *(const f32x4*)(gp + 4);
            }
#pragma unroll
            for (int i = 0; i < 8; ++i) {
                const int r  = (g * 8 + i) * 8 + (l >> 3);
                const int cb = (l & 7) * 16;
                f16x8 vv = *(const f16x8*)(slice + r * 128 + (cb ^ ((r & 7) << 4)));
                f16x8 o;
#pragma unroll
                for (int j = 0; j < 4; ++j) {
                    o[j]     = (f16)((float)vv[j] * ga[i][0][j]);
                    o[j + 4] = (f16)((float)vv[j + 4] * ga[i][1][j]);
                }
                *(f16x8*)&g_sg[(size_t)(crow0 + r) * TT + ccol0 + (l & 7) * 8] = o;
            }
        }
    } else {
        f16* dst;
        int ld;
        if constexpr (EPI == 0) { dst = (sel == 0) ? g_q : (sel == 1) ? g_k : g_v; ld = 1024; }
        else                    { dst = g_part[blockIdx.z]; ld = 1024; }
#pragma unroll
        for (int i = 0; i < 16; ++i) {
            const int r  = i * 8 + (l >> 3);
            const int cb = (l & 7) * 16;
            f16x8 vv = *(const f16x8*)(slice + r * 128 + (cb ^ ((r & 7) << 4)));
            *(f16x8*)&dst[(size_t)(crow0 + r) * ld + cb0 + (l & 7) * 8] = vv;
        }
    }
}

// sum 4 split-K f16 partials -> g_ret f16
__global__ __launch_bounds__(256) void reduce_parts() {
    size_t i = (size_t)(blockIdx.x * 256 + threadIdx.x) * 8;
    f16x8 a = *(const f16x8*)&g_part[0][i];
    f16x8 b = *(const f16x8*)&g_part[1][i];
    f16x8 cc = *(const f16x8*)&g_part[2][i];
    f16x8 d = *(const f16x8*)&g_part[3][i];
    f16x8 o;
#pragma unroll
    for (int j = 0; j < 8; ++j)
        o[j] = (f16)((float)a[j] + (float)b[j] + (float)cc[j] + (float)d[j]);
    *(f16x8*)&g_ret[i] = o;
}

// sum 4 split-K f16 partials + bias + PReLU -> out f32
__global__ __launch_bounds__(256) void reduce_out(const float* __restrict__ br,
                                                  const float* __restrict__ prelu_a,
                                                  float* __restrict__ out) {
    size_t i = (size_t)(blockIdx.x * 256 + threadIdx.x) * 8;
    f16x8 a = *(const f16x8*)&g_part[0][i];
    f16x8 b = *(const f16x8*)&g_part[1][i];
    f16x8 cc = *(const f16x8*)&g_part[2][i];
    f16x8 d = *(const f16x8*)&g_part[3][i];
    const float pa = *prelu_a;
    const int col = (int)(i & 1023);
    const f32x4 b0 = *(const f32x4*)&br[col];
    const f32x4 b1 = *(const f32x4*)&br[col + 4];
    f32x4 o0, o1;
#pragma unroll
    for (int j = 0; j < 4; ++j) {
        float s = (float)a[j] + (float)b[j] + (float)cc[j] + (float)d[j] + b0[j];
        o0[j] = (s >= 0.f) ? s : pa * s;
    }
#pragma unroll
    for (int j = 0; j < 4; ++j) {
        float s = (float)a[j + 4] + (float)b[j + 4] + (float)cc[j + 4] + (float)d[j + 4] + b1[j];
        o1[j] = (s >= 0.f) ? s : pa * s;
    }
    *(f32x4*)&out[i] = o0;
    *(f32x4*)&out[i + 4] = o1;
}

extern "C" void kernel_launch(void* const* d_in, const int* in_sizes, int n_in,
                              void* d_out, int out_size, void* d_ws, size_t ws_size,
                              hipStream_t stream) {
    const float* x     = (const float*)d_in[0];
    const float* gamma = (const float*)d_in[1];
    const float* Wq    = (const float*)d_in[2];
    const float* bq    = (const float*)d_in[3];
    const float* Wk    = (const float*)d_in[4];
    const float* bk    = (const float*)d_in[5];
    const float* Wv    = (const float*)d_in[6];
    const float* bv    = (const float*)d_in[7];
    const float* Wr    = (const float*)d_in[8];
    const float* br    = (const float*)d_in[9];
    const float* pa    = (const float*)d_in[10];
    float* out = (float*)d_out;

    prep_cast_x<<<TT * DIN / 8 / 256, 256, 0, stream>>>(x);
    prep_transpose<<<dim3(16, 16, 4), 256, 0, stream>>>(Wq, Wk, Wv, Wr);

    // EPI 0: qkv  M=4096 N=3072  (192 blocks)
    gemm8<0><<<dim3(12, 16), 512, 0, stream>>>(gamma, bq, bk, bv);
    transpose_v<<<dim3(16, 64), 256, 0, stream>>>();
    // EPI 1: g_sg = gamma .* (q k^T)  M=4096 N=4096  (256 blocks)
    gemm8<1><<<dim3(16, 16), 512, 0, stream>>>(gamma, bq, bk, bv);
    // EPI 2: retained partials, split-K=4 over K=4096  (256 blocks)
    gemm8<2><<<dim3(4, 16, 4), 512, 0, stream>>>(gamma, bq, bk, bv);
    reduce_parts<<<TT * DIN / 8 / 256, 256, 0, stream>>>();
    // EPI 3: out partials, split-K=4 over K=1024 (NT=4)  (256 blocks)
    gemm8<3><<<dim3(4, 16, 4), 512, 0, stream>>>(gamma, bq, bk, bv);
    reduce_out<<<TT * DIN / 8 / 256, 256, 0, stream>>>(br, pa, out);
}

// Round 16
// 175.104 us; speedup vs baseline: 1.0760x; 1.0103x over previous
//
#include <hip/hip_runtime.h>

#define TT 4096
#define DIN 1024

typedef _Float16 f16;
typedef __attribute__((ext_vector_type(8))) _Float16 f16x8;
typedef __attribute__((ext_vector_type(4))) _Float16 f16x4;
typedef __attribute__((ext_vector_type(4))) float f32x4;

// ---- device-global scratch ----
__device__ f16 g_xh[TT * DIN];               // x cast to f16            8 MB
__device__ f16 g_wqkvT[3 * DIN * DIN];       // [Wq^T|Wk^T|Wv^T] f16     6 MB
__device__ f16 g_wrT[DIN * DIN];             // Wr^T f16                 2 MB
__device__ f16 g_q[TT * DIN];                // q                        8 MB
__device__ f16 g_k[TT * DIN];                // k                        8 MB
__device__ f16 g_v[TT * DIN];                // v row-major              8 MB
__device__ f16 g_vT[DIN * TT];               // v transposed             8 MB
__device__ f16 g_sg[(size_t)TT * TT];        // gamma .* (q k^T)        32 MB
__device__ f16 g_part[4][TT * DIN];          // split-K partials f16    32 MB
__device__ f16 g_ret[TT * DIN];              // retained                 8 MB

// ---- prep kernels ----
__global__ __launch_bounds__(256) void prep_cast_x(const float* __restrict__ x) {
    int i = (blockIdx.x * 256 + threadIdx.x) * 8;
    f32x4 a = *(const f32x4*)&x[i];
    f32x4 b = *(const f32x4*)&x[i + 4];
    f16x8 o;
#pragma unroll
    for (int j = 0; j < 4; ++j) { o[j] = (f16)a[j]; o[j + 4] = (f16)b[j]; }
    *(f16x8*)&g_xh[i] = o;
}

// LDS-tiled transpose-cast: dst[j][k] = (f16)src[k][j], 64x64 f32 tiles.
__global__ __launch_bounds__(256) void prep_transpose(const float* __restrict__ Wq,
                                                      const float* __restrict__ Wk,
                                                      const float* __restrict__ Wv,
                                                      const float* __restrict__ Wr) {
    __shared__ float tt[64][68];                     // 272B rows: 16B-aligned
    const int which = blockIdx.z;
    const float* src = (which == 0) ? Wq : (which == 1) ? Wk : (which == 2) ? Wv : Wr;
    f16* dst = (which < 3) ? (g_wqkvT + (size_t)which * DIN * DIN) : g_wrT;
    const int t = threadIdx.x;
    const int r = t >> 2;                            // 0..63
    const int c0 = (t & 3) * 4;
#pragma unroll
    for (int ch = 0; ch < 4; ++ch)
        *(f32x4*)&tt[r][c0 + ch * 16] =
            *(const f32x4*)&src[(size_t)(blockIdx.y * 64 + r) * DIN + blockIdx.x * 64 + c0 + ch * 16];
    __syncthreads();
#pragma unroll
    for (int p = 0; p < 2; ++p) {
        const int j  = (t >> 3) + p * 32;            // dst row (= src col)
        const int k0 = (t & 7) * 8;
        f16x8 o;
#pragma unroll
        for (int jj = 0; jj < 8; ++jj) o[jj] = (f16)tt[k0 + jj][j];
        *(f16x8*)&dst[(size_t)(blockIdx.x * 64 + j) * DIN + blockIdx.y * 64 + k0] = o;
    }
}

// LDS-tiled transpose: g_v [4096][1024] -> g_vT [1024][4096]
__global__ __launch_bounds__(256) void transpose_v() {
    __shared__ f16 t[64][72];
    const int bc = blockIdx.x;
    const int br = blockIdx.y;
    const int tdx = threadIdx.x;
    const int r0 = tdx >> 3;
    const int c8 = (tdx & 7) * 8;
#pragma unroll
    for (int p = 0; p < 2; ++p) {
        int r = r0 + p * 32;
        *(f16x8*)&t[r][c8] = *(const f16x8*)&g_v[(size_t)(br * 64 + r) * DIN + bc * 64 + c8];
    }
    __syncthreads();
#pragma unroll
    for (int p = 0; p < 2; ++p) {
        int c = r0 + p * 32;
        f16x8 v;
#pragma unroll
        for (int j = 0; j < 8; ++j) v[j] = t[c8 + j][c];
        *(f16x8*)&g_vT[(size_t)(bc * 64 + c) * TT + br * 64 + c8] = v;
    }
}

// ---- async global->LDS, 16B per lane, wave-uniform LDS base ----
__device__ __forceinline__ void gload_lds16(const void* g, void* l) {
    __builtin_amdgcn_global_load_lds(
        (const __attribute__((address_space(1))) unsigned int*)g,
        (__attribute__((address_space(3))) unsigned int*)l,
        16, 0, 0);
}

// ================= 256x256 8-phase GEMM, C = A * B^T =================
// BK=64, 8 waves (2Mx4N), per-wave 128x64 out. LDS: 2 tile-buffers x 64KB.
// Swizzle: byte ^= (row&7)<<4 on stage SOURCE col and ds_read col.
// vmcnt ledger: steady kt outstanding = B(kt)4 + A(kt)4 + B(kt+1)4 = 12 ->
// vmcnt(4). Last kt: full drain vmcnt(0) (race fix, r3).
//
// Epilogue: per-wave LDS micro-repack -> packed f16x8 stores (r7, validated).
// EPI 0: -> q|k|v f16 (+bias), select by bx>>2
// EPI 1: -> g_sg = gamma .* S ; gamma fused, SOFTWARE-PIPELINED (r16):
//         group-A loads issued BEFORE the phase-1 repack (latency hidden
//         under 128 LDS writes); group-B issued right after (acc dead),
//         in flight behind group-A's consume. No exposed HBM stall.
// EPI 2: -> g_part[z] f16, split-K over blockIdx.z (K=4096/4)
// EPI 3: -> g_part[z] f16, split-K over blockIdx.z (K=1024/4, NT=4)
template <int EPI>
__global__ __launch_bounds__(512, 2) void gemm8(const float* __restrict__ gamma,
                                                const float* __restrict__ bq,
                                                const float* __restrict__ bk,
                                                const float* __restrict__ bv) {
    constexpr int NT  = (EPI == 3) ? 4 : 16;         // K-tiles of 64
    constexpr int ld2A = (EPI == 2) ? 8192 : 2048;   // A row bytes
    constexpr int ld2B = (EPI == 2) ? 8192 : 2048;   // B row bytes

    const f16* Ap = (EPI == 0) ? g_xh : (EPI == 1) ? g_q : (EPI == 2) ? g_sg : g_ret;
    const f16* Bp = (EPI == 0) ? g_wqkvT : (EPI == 1) ? g_k : (EPI == 2) ? g_vT : g_wrT;
    const int kb_base = (EPI == 2) ? blockIdx.z * 2048
                      : (EPI == 3) ? blockIdx.z * 512 : 0;   // byte offset of K-slice

    __shared__ __align__(16) char smem[131072];

    const int t = threadIdx.x;
    const int w = t >> 6, l = t & 63;
    const int wr = w >> 2, wc = w & 3;               // 2M x 4N waves
    const int fr = l & 15;
    const int fkb = (l >> 4) * 16;                   // fragment k-byte (0..48)

    // XCD swizzle over (x,y) (bijective: all grids have nwg%8==0)
    const int nx = gridDim.x;
    const int lin = blockIdx.y * nx + blockIdx.x;
    const int cpx = (nx * gridDim.y) >> 3;
    const int sw = (lin & 7) * cpx + (lin >> 3);
    const int bx = sw % nx, by = sw / nx;
    const int arow0 = by * 256;
    const int bcol0 = bx * 256;

    auto stage = [&](const f16* M, int ld2, int row0, int kb0, int dstoff) {
#pragma unroll
        for (int r = 0; r < 2; ++r) {
            int off = r * 8192 + w * 1024;           // wave-uniform LDS offset
            int row = (off + l * 16) >> 7;
            int cb  = (l & 7) * 16;
            int scb = cb ^ ((row & 7) << 4);         // inverse-swizzle the SOURCE
            const char* src = (const char*)M + (size_t)(row0 + row) * ld2 + kb0 + scb;
            gload_lds16(src, smem + dstoff + off);
        }
    };

    auto ldsA = [&](int c, int m, int ks) -> f16x8 {
        int lr = m * 16 + fr;
        int kb = ks * 64 + fkb;
        return *(const f16x8*)(smem + c * 65536 + wr * 16384 + lr * 128 + (kb ^ ((lr & 7) << 4)));
    };
    auto ldsB = [&](int c, int n, int ks) -> f16x8 {
        int lc = (wc & 1) * 64 + n * 16 + fr;
        int kb = ks * 64 + fkb;
        return *(const f16x8*)(smem + c * 65536 + 32768 + (wc >> 1) * 16384 + lc * 128 + (kb ^ ((lc & 7) << 4)));
    };

#define KB(kt) (kb_base + (kt) * 128)

    // prologue: tile0 complete + tile1 B-halves (12 loads/thread in flight)
    stage(Ap, ld2A, arow0,       KB(0), 0);
    stage(Ap, ld2A, arow0 + 128, KB(0), 16384);
    stage(Bp, ld2B, bcol0,       KB(0), 32768);
    stage(Bp, ld2B, bcol0 + 128, KB(0), 49152);
    stage(Bp, ld2B, bcol0,       KB(1), 65536 + 32768);
    stage(Bp, ld2B, bcol0 + 128, KB(1), 65536 + 49152);

    f32x4 acc[8][4] = {};
    f16x8 bf[4][2];

#define GPHASE(MB, STAGE_STMT)                                              \
    {                                                                       \
        f16x8 af[2][2];                                                     \
        _Pragma("unroll") for (int i = 0; i < 2; ++i)                       \
            _Pragma("unroll") for (int ks = 0; ks < 2; ++ks)                \
                af[i][ks] = ldsA(c, (MB) + i, ks);                          \
        STAGE_STMT;                                                         \
        __builtin_amdgcn_s_barrier();                                       \
        __builtin_amdgcn_s_setprio(1);                                      \
        _Pragma("unroll") for (int i = 0; i < 2; ++i)                       \
            _Pragma("unroll") for (int n = 0; n < 4; ++n)                   \
                _Pragma("unroll") for (int ks = 0; ks < 2; ++ks)            \
                    acc[(MB) + i][n] = __builtin_amdgcn_mfma_f32_16x16x32_f16( \
                        af[i][ks], bf[n][ks], acc[(MB) + i][n], 0, 0, 0);   \
        __builtin_amdgcn_s_setprio(0);                                      \
        __builtin_amdgcn_s_barrier();                                       \
    }

    for (int kt = 0; kt < NT; ++kt) {
        const int c = kt & 1;
        if (kt == NT - 1) asm volatile("s_waitcnt vmcnt(0)" ::: "memory");
        else              asm volatile("s_waitcnt vmcnt(4)" ::: "memory");
        __builtin_amdgcn_s_barrier();
#pragma unroll
        for (int n = 0; n < 4; ++n)
#pragma unroll
            for (int ks = 0; ks < 2; ++ks) bf[n][ks] = ldsB(c, n, ks);
        GPHASE(0, if (kt + 1 < NT) stage(Ap, ld2A, arow0,       KB(kt + 1), (c ^ 1) * 65536))
        GPHASE(2, if (kt + 1 < NT) stage(Ap, ld2A, arow0 + 128, KB(kt + 1), (c ^ 1) * 65536 + 16384))
        GPHASE(4, if (kt + 2 < NT) stage(Bp, ld2B, bcol0,       KB(kt + 2), c * 65536 + 32768))
        GPHASE(6, if (kt + 2 < NT) stage(Bp, ld2B, bcol0 + 128, KB(kt + 2), c * 65536 + 49152))
    }
#undef GPHASE
#undef KB

    // ------------- per-wave LDS micro-repack epilogue -------------
    __syncthreads();                                 // K-loop LDS fully retired
    char* slice = smem + w * 16384;                  // wave-private f16[128][64]
    const int rb = (l >> 4) * 4;
    const int crow0 = arow0 + wr * 128;
    const int ccol0 = bcol0 + wc * 64;

    const int sel = (EPI == 0) ? (bx >> 2) : 0;      // 0=q 1=k 2=v
    const float* bias0 = (EPI == 0) ? ((sel == 0) ? bq : (sel == 1) ? bk : bv) : nullptr;
    const int cb0 = (EPI == 0) ? (ccol0 - sel * 1024) : ccol0;

    // EPI1: issue group-A gamma loads EARLY — latency hides under phase-1
    f32x4 gA[8][2];
    if constexpr (EPI == 1) {
#pragma unroll
        for (int i = 0; i < 8; ++i) {
            const int r = i * 8 + (l >> 3);
            const float* gp = &gamma[(size_t)(crow0 + r) * TT + ccol0 + (l & 7) * 8];
            gA[i][0] = *(const f32x4*)gp;
            gA[i][1] = *(const f32x4*)(gp + 4);
        }
    }

    // phase 1: acc (+bias) -> f16 into swizzled wave slice
#pragma unroll
    for (int m = 0; m < 8; ++m)
#pragma unroll
        for (int n = 0; n < 4; ++n) {
            float bsum = 0.f;
            if constexpr (EPI == 0) bsum = bias0[cb0 + n * 16 + fr];
#pragma unroll
            for (int j = 0; j < 4; ++j) {
                const int lr = m * 16 + rb + j;
                const int lcb = (n * 16 + fr) * 2;
                *(f16*)(slice + lr * 128 + (lcb ^ ((lr & 7) << 4))) = (f16)(acc[m][n][j] + bsum);
            }
        }
    asm volatile("s_waitcnt lgkmcnt(0)" ::: "memory");   // wave-internal writes visible
    __builtin_amdgcn_sched_barrier(0);                    // rule 18: pin reads after wait

    // phase 2: packed coalesced stores (16B/lane, 8x128B segments/inst)
    if constexpr (EPI == 1) {
        // issue group-B loads now (acc dead; they fly behind group-A consume)
        f32x4 gB[8][2];
#pragma unroll
        for (int i = 0; i < 8; ++i) {
            const int r = (8 + i) * 8 + (l >> 3);
            const float* gp = &gamma[(size_t)(crow0 + r) * TT + ccol0 + (l & 7) * 8];
            gB[i][0] = *(const f32x4*)gp;
            gB[i][1] = *(const f32x4*)(gp + 4);
        }
        // consume group A
#pragma unroll
        for (int i = 0; i < 8; ++i) {
            const int r  = i * 8 + (l >> 3);
            const int cb = (l & 7) * 16;
            f16x8 vv = *(const f16x8*)(slice + r * 128 + (cb ^ ((r & 7) << 4)));
            f16x8 o;
#pragma unroll
            for (int j = 0; j < 4; ++j) {
                o[j]     = (f16)((float)vv[j] * gA[i][0][j]);
                o[j + 4] = (f16)((float)vv[j + 4] * gA[i][1][j]);
            }
            *(f16x8*)&g_sg[(size_t)(crow0 + r) * TT + ccol0 + (l & 7) * 8] = o;
        }
        // consume group B
#pragma unroll
        for (int i = 0; i < 8; ++i) {
            const int r  = (8 + i) * 8 + (l >> 3);
            const int cb = (l & 7) * 16;
            f16x8 vv = *(const f16x8*)(slice + r * 128 + (cb ^ ((r & 7) << 4)));
            f16x8 o;
#pragma unroll
            for (int j = 0; j < 4; ++j) {
                o[j]     = (f16)((float)vv[j] * gB[i][0][j]);
                o[j + 4] = (f16)((float)vv[j + 4] * gB[i][1][j]);
            }
            *(f16x8*)&g_sg[(size_t)(crow0 + r) * TT + ccol0 + (l & 7) * 8] = o;
        }
    } else {
        f16* dst;
        int ld;
        if constexpr (EPI == 0) { dst = (sel == 0) ? g_q : (sel == 1) ? g_k : g_v; ld = 1024; }
        else                    { dst = g_part[blockIdx.z]; ld = 1024; }
#pragma unroll
        for (int i = 0; i < 16; ++i) {
            const int r  = i * 8 + (l >> 3);
            const int cb = (l & 7) * 16;
            f16x8 vv = *(const f16x8*)(slice + r * 128 + (cb ^ ((r & 7) << 4)));
            *(f16x8*)&dst[(size_t)(crow0 + r) * ld + cb0 + (l & 7) * 8] = vv;
        }
    }
}

// sum 4 split-K f16 partials -> g_ret f16
__global__ __launch_bounds__(256) void reduce_parts() {
    size_t i = (size_t)(blockIdx.x * 256 + threadIdx.x) * 8;
    f16x8 a = *(const f16x8*)&g_part[0][i];
    f16x8 b = *(const f16x8*)&g_part[1][i];
    f16x8 cc = *(const f16x8*)&g_part[2][i];
    f16x8 d = *(const f16x8*)&g_part[3][i];
    f16x8 o;
#pragma unroll
    for (int j = 0; j < 8; ++j)
        o[j] = (f16)((float)a[j] + (float)b[j] + (float)cc[j] + (float)d[j]);
    *(f16x8*)&g_ret[i] = o;
}

// sum 4 split-K f16 partials + bias + PReLU -> out f32
__global__ __launch_bounds__(256) void reduce_out(const float* __restrict__ br,
                                                  const float* __restrict__ prelu_a,
                                                  float* __restrict__ out) {
    size_t i = (size_t)(blockIdx.x * 256 + threadIdx.x) * 8;
    f16x8 a = *(const f16x8*)&g_part[0][i];
    f16x8 b = *(const f16x8*)&g_part[1][i];
    f16x8 cc = *(const f16x8*)&g_part[2][i];
    f16x8 d = *(const f16x8*)&g_part[3][i];
    const float pa = *prelu_a;
    const int col = (int)(i & 1023);
    const f32x4 b0 = *(const f32x4*)&br[col];
    const f32x4 b1 = *(const f32x4*)&br[col + 4];
    f32x4 o0, o1;
#pragma unroll
    for (int j = 0; j < 4; ++j) {
        float s = (float)a[j] + (float)b[j] + (float)cc[j] + (float)d[j] + b0[j];
        o0[j] = (s >= 0.f) ? s : pa * s;
    }
#pragma unroll
    for (int j = 0; j < 4; ++j) {
        float s = (float)a[j + 4] + (float)b[j + 4] + (float)cc[j + 4] + (float)d[j + 4] + b1[j];
        o1[j] = (s >= 0.f) ? s : pa * s;
    }
    *(f32x4*)&out[i] = o0;
    *(f32x4*)&out[i + 4] = o1;
}

extern "C" void kernel_launch(void* const* d_in, const int* in_sizes, int n_in,
                              void* d_out, int out_size, void* d_ws, size_t ws_size,
                              hipStream_t stream) {
    const float* x     = (const float*)d_in[0];
    const float* gamma = (const float*)d_in[1];
    const float* Wq    = (const float*)d_in[2];
    const float* bq    = (const float*)d_in[3];
    const float* Wk    = (const float*)d_in[4];
    const float* bk    = (const float*)d_in[5];
    const float* Wv    = (const float*)d_in[6];
    const float* bv    = (const float*)d_in[7];
    const float* Wr    = (const float*)d_in[8];
    const float* br    = (const float*)d_in[9];
    const float* pa    = (const float*)d_in[10];
    float* out = (float*)d_out;

    prep_cast_x<<<TT * DIN / 8 / 256, 256, 0, stream>>>(x);
    prep_transpose<<<dim3(16, 16, 4), 256, 0, stream>>>(Wq, Wk, Wv, Wr);

    // EPI 0: qkv  M=4096 N=3072  (192 blocks)
    gemm8<0><<<dim3(12, 16), 512, 0, stream>>>(gamma, bq, bk, bv);
    transpose_v<<<dim3(16, 64), 256, 0, stream>>>();
    // EPI 1: g_sg = gamma .* (q k^T)  M=4096 N=4096  (256 blocks)
    gemm8<1><<<dim3(16, 16), 512, 0, stream>>>(gamma, bq, bk, bv);
    // EPI 2: retained partials, split-K=4 over K=4096  (256 blocks)
    gemm8<2><<<dim3(4, 16, 4), 512, 0, stream>>>(gamma, bq, bk, bv);
    reduce_parts<<<TT * DIN / 8 / 256, 256, 0, stream>>>();
    // EPI 3: out partials, split-K=4 over K=1024 (NT=4)  (256 blocks)
    gemm8<3><<<dim3(4, 16, 4), 512, 0, stream>>>(gamma, bq, bk, bv);
    reduce_out<<<TT * DIN / 8 / 256, 256, 0, stream>>>(br, pa, out);
}

// Round 17
// 174.861 us; speedup vs baseline: 1.0775x; 1.0014x over previous
//
#include <hip/hip_runtime.h>

#define TT 4096
#define DIN 1024

typedef _Float16 f16;
typedef __attribute__((ext_vector_type(8))) _Float16 f16x8;
typedef __attribute__((ext_vector_type(4))) _Float16 f16x4;
typedef __attribute__((ext_vector_type(4))) float f32x4;

// ---- device-global scratch ----
__device__ f16 g_xh[TT * DIN];               // x cast to f16            8 MB
__device__ f16 g_wqkvT[3 * DIN * DIN];       // [Wq^T|Wk^T|Wv^T] f16     6 MB
__device__ f16 g_wrT[DIN * DIN];             // Wr^T f16                 2 MB
__device__ f16 g_q[TT * DIN];                // q                        8 MB
__device__ f16 g_k[TT * DIN];                // k                        8 MB
__device__ f16 g_v[TT * DIN];                // v row-major              8 MB
__device__ f16 g_vT[DIN * TT];               // v transposed             8 MB
__device__ f16 g_sg[(size_t)TT * TT];        // gamma .* (q k^T)        32 MB
__device__ f16 g_part[4][TT * DIN];          // split-K partials f16    32 MB
__device__ f16 g_ret[TT * DIN];              // retained                 8 MB

// ---- prep kernels ----
__global__ __launch_bounds__(256) void prep_cast_x(const float* __restrict__ x) {
    int i = (blockIdx.x * 256 + threadIdx.x) * 8;
    f32x4 a = *(const f32x4*)&x[i];
    f32x4 b = *(const f32x4*)&x[i + 4];
    f16x8 o;
#pragma unroll
    for (int j = 0; j < 4; ++j) { o[j] = (f16)a[j]; o[j + 4] = (f16)b[j]; }
    *(f16x8*)&g_xh[i] = o;
}

// LDS-tiled transpose-cast: dst[j][k] = (f16)src[k][j], 64x64 f32 tiles.
__global__ __launch_bounds__(256) void prep_transpose(const float* __restrict__ Wq,
                                                      const float* __restrict__ Wk,
                                                      const float* __restrict__ Wv,
                                                      const float* __restrict__ Wr) {
    __shared__ float tt[64][68];                     // 272B rows: 16B-aligned
    const int which = blockIdx.z;
    const float* src = (which == 0) ? Wq : (which == 1) ? Wk : (which == 2) ? Wv : Wr;
    f16* dst = (which < 3) ? (g_wqkvT + (size_t)which * DIN * DIN) : g_wrT;
    const int t = threadIdx.x;
    const int r = t >> 2;                            // 0..63
    const int c0 = (t & 3) * 4;
#pragma unroll
    for (int ch = 0; ch < 4; ++ch)
        *(f32x4*)&tt[r][c0 + ch * 16] =
            *(const f32x4*)&src[(size_t)(blockIdx.y * 64 + r) * DIN + blockIdx.x * 64 + c0 + ch * 16];
    __syncthreads();
#pragma unroll
    for (int p = 0; p < 2; ++p) {
        const int j  = (t >> 3) + p * 32;            // dst row (= src col)
        const int k0 = (t & 7) * 8;
        f16x8 o;
#pragma unroll
        for (int jj = 0; jj < 8; ++jj) o[jj] = (f16)tt[k0 + jj][j];
        *(f16x8*)&dst[(size_t)(blockIdx.x * 64 + j) * DIN + blockIdx.y * 64 + k0] = o;
    }
}

// LDS-tiled transpose: g_v [4096][1024] -> g_vT [1024][4096]
__global__ __launch_bounds__(256) void transpose_v() {
    __shared__ f16 t[64][72];
    const int bc = blockIdx.x;
    const int br = blockIdx.y;
    const int tdx = threadIdx.x;
    const int r0 = tdx >> 3;
    const int c8 = (tdx & 7) * 8;
#pragma unroll
    for (int p = 0; p < 2; ++p) {
        int r = r0 + p * 32;
        *(f16x8*)&t[r][c8] = *(const f16x8*)&g_v[(size_t)(br * 64 + r) * DIN + bc * 64 + c8];
    }
    __syncthreads();
#pragma unroll
    for (int p = 0; p < 2; ++p) {
        int c = r0 + p * 32;
        f16x8 v;
#pragma unroll
        for (int j = 0; j < 8; ++j) v[j] = t[c8 + j][c];
        *(f16x8*)&g_vT[(size_t)(bc * 64 + c) * TT + br * 64 + c8] = v;
    }
}

// ---- async global->LDS, 16B per lane, wave-uniform LDS base ----
__device__ __forceinline__ void gload_lds16(const void* g, void* l) {
    __builtin_amdgcn_global_load_lds(
        (const __attribute__((address_space(1))) unsigned int*)g,
        (__attribute__((address_space(3))) unsigned int*)l,
        16, 0, 0);
}

// ================= 256x256 8-phase GEMM, C = A * B^T =================
// BK=64, 8 waves (2Mx4N), per-wave 128x64 out. LDS: 2 tile-buffers x 64KB.
// Swizzle: byte ^= (row&7)<<4 on stage SOURCE col and ds_read col.
//
// r17 phase packing (m201-faithful): NO separate top-of-loop vmcnt+barrier.
// ph1 absorbs the 8 bf reads (12-read phase); ph4 carries the counted vmcnt
// just before its closing barrier, which doubles as the next-tile sync.
// Ledger (induction-verified, NT=16 and NT=4): at ph4's vmcnt, outstanding =
// B(kt+1)4 + A(kt+1)4 + B(kt+2)4 = 12 -> vmcnt(4) drains the 8 needed for
// kt+1, keeps B(kt+2). Tails: kt >= NT-2 -> vmcnt(0) (B(kt+2) never staged).
// Prologue: A(0),B(0),B(1) staged; vmcnt(4)+barrier covers kt=0.
//
// Epilogue: per-wave LDS micro-repack -> packed f16x8 stores (r7, validated).
// EPI 0: -> q|k|v f16 (+bias), select by bx>>2
// EPI 1: -> g_sg = gamma .* S ; gamma fused + software-pipelined (r16):
//         group-A loads before the repack, group-B after; no exposed stall.
// EPI 2: -> g_part[z] f16, split-K over blockIdx.z (K=4096/4)
// EPI 3: -> g_part[z] f16, split-K over blockIdx.z (K=1024/4, NT=4)
template <int EPI>
__global__ __launch_bounds__(512, 2) void gemm8(const float* __restrict__ gamma,
                                                const float* __restrict__ bq,
                                                const float* __restrict__ bk,
                                                const float* __restrict__ bv) {
    constexpr int NT  = (EPI == 3) ? 4 : 16;         // K-tiles of 64
    constexpr int ld2A = (EPI == 2) ? 8192 : 2048;   // A row bytes
    constexpr int ld2B = (EPI == 2) ? 8192 : 2048;   // B row bytes

    const f16* Ap = (EPI == 0) ? g_xh : (EPI == 1) ? g_q : (EPI == 2) ? g_sg : g_ret;
    const f16* Bp = (EPI == 0) ? g_wqkvT : (EPI == 1) ? g_k : (EPI == 2) ? g_vT : g_wrT;
    const int kb_base = (EPI == 2) ? blockIdx.z * 2048
                      : (EPI == 3) ? blockIdx.z * 512 : 0;   // byte offset of K-slice

    __shared__ __align__(16) char smem[131072];

    const int t = threadIdx.x;
    const int w = t >> 6, l = t & 63;
    const int wr = w >> 2, wc = w & 3;               // 2M x 4N waves
    const int fr = l & 15;
    const int fkb = (l >> 4) * 16;                   // fragment k-byte (0..48)

    // XCD swizzle over (x,y) (bijective: all grids have nwg%8==0)
    const int nx = gridDim.x;
    const int lin = blockIdx.y * nx + blockIdx.x;
    const int cpx = (nx * gridDim.y) >> 3;
    const int sw = (lin & 7) * cpx + (lin >> 3);
    const int bx = sw % nx, by = sw / nx;
    const int arow0 = by * 256;
    const int bcol0 = bx * 256;

    auto stage = [&](const f16* M, int ld2, int row0, int kb0, int dstoff) {
#pragma unroll
        for (int r = 0; r < 2; ++r) {
            int off = r * 8192 + w * 1024;           // wave-uniform LDS offset
            int row = (off + l * 16) >> 7;
            int cb  = (l & 7) * 16;
            int scb = cb ^ ((row & 7) << 4);         // inverse-swizzle the SOURCE
            const char* src = (const char*)M + (size_t)(row0 + row) * ld2 + kb0 + scb;
            gload_lds16(src, smem + dstoff + off);
        }
    };

    auto ldsA = [&](int c, int m, int ks) -> f16x8 {
        int lr = m * 16 + fr;
        int kb = ks * 64 + fkb;
        return *(const f16x8*)(smem + c * 65536 + wr * 16384 + lr * 128 + (kb ^ ((lr & 7) << 4)));
    };
    auto ldsB = [&](int c, int n, int ks) -> f16x8 {
        int lc = (wc & 1) * 64 + n * 16 + fr;
        int kb = ks * 64 + fkb;
        return *(const f16x8*)(smem + c * 65536 + 32768 + (wc >> 1) * 16384 + lc * 128 + (kb ^ ((lc & 7) << 4)));
    };

#define KB(kt) (kb_base + (kt) * 128)

    // prologue: tile0 complete + tile1 B-halves (12 loads/thread in flight)
    stage(Ap, ld2A, arow0,       KB(0), 0);
    stage(Ap, ld2A, arow0 + 128, KB(0), 16384);
    stage(Bp, ld2B, bcol0,       KB(0), 32768);
    stage(Bp, ld2B, bcol0 + 128, KB(0), 49152);
    stage(Bp, ld2B, bcol0,       KB(1), 65536 + 32768);
    stage(Bp, ld2B, bcol0 + 128, KB(1), 65536 + 49152);

    f32x4 acc[8][4] = {};
    f16x8 bf[4][2];

    // covers kt=0 (drains A(0),B(0); keeps B(1))
    asm volatile("s_waitcnt vmcnt(4)" ::: "memory");
    __builtin_amdgcn_s_barrier();

#define GPHASE(MB, PRE_STMT, STAGE_STMT, POST_STMT)                         \
    {                                                                       \
        PRE_STMT;                                                           \
        f16x8 af[2][2];                                                     \
        _Pragma("unroll") for (int i = 0; i < 2; ++i)                       \
            _Pragma("unroll") for (int ks = 0; ks < 2; ++ks)                \
                af[i][ks] = ldsA(c, (MB) + i, ks);                          \
        STAGE_STMT;                                                         \
        __builtin_amdgcn_s_barrier();                                       \
        __builtin_amdgcn_s_setprio(1);                                      \
        _Pragma("unroll") for (int i = 0; i < 2; ++i)                       \
            _Pragma("unroll") for (int n = 0; n < 4; ++n)                   \
                _Pragma("unroll") for (int ks = 0; ks < 2; ++ks)            \
                    acc[(MB) + i][n] = __builtin_amdgcn_mfma_f32_16x16x32_f16( \
                        af[i][ks], bf[n][ks], acc[(MB) + i][n], 0, 0, 0);   \
        __builtin_amdgcn_s_setprio(0);                                      \
        POST_STMT;                                                          \
        __builtin_amdgcn_s_barrier();                                       \
    }

#define LOADB()                                                             \
    _Pragma("unroll") for (int n = 0; n < 4; ++n)                           \
        _Pragma("unroll") for (int ks = 0; ks < 2; ++ks)                    \
            bf[n][ks] = ldsB(c, n, ks)

    for (int kt = 0; kt < NT; ++kt) {
        const int c = kt & 1;
        // ph1: 12-read phase (bf x8 + af m0,m1) + stage A0(kt+1)
        GPHASE(0, LOADB(),
               if (kt + 1 < NT) stage(Ap, ld2A, arow0,       KB(kt + 1), (c ^ 1) * 65536), )
        // ph2
        GPHASE(2, ,
               if (kt + 1 < NT) stage(Ap, ld2A, arow0 + 128, KB(kt + 1), (c ^ 1) * 65536 + 16384), )
        // ph3
        GPHASE(4, ,
               if (kt + 2 < NT) stage(Bp, ld2B, bcol0,       KB(kt + 2), c * 65536 + 32768), )
        // ph4: counted vmcnt for tile kt+1 before the closing barrier
        GPHASE(6, ,
               if (kt + 2 < NT) stage(Bp, ld2B, bcol0 + 128, KB(kt + 2), c * 65536 + 49152),
               if (kt >= NT - 2) { asm volatile("s_waitcnt vmcnt(0)" ::: "memory"); }
               else              { asm volatile("s_waitcnt vmcnt(4)" ::: "memory"); })
    }
#undef LOADB
#undef GPHASE
#undef KB

    // ------------- per-wave LDS micro-repack epilogue -------------
    __syncthreads();                                 // K-loop LDS fully retired
    char* slice = smem + w * 16384;                  // wave-private f16[128][64]
    const int rb = (l >> 4) * 4;
    const int crow0 = arow0 + wr * 128;
    const int ccol0 = bcol0 + wc * 64;

    const int sel = (EPI == 0) ? (bx >> 2) : 0;      // 0=q 1=k 2=v
    const float* bias0 = (EPI == 0) ? ((sel == 0) ? bq : (sel == 1) ? bk : bv) : nullptr;
    const int cb0 = (EPI == 0) ? (ccol0 - sel * 1024) : ccol0;

    // EPI1: issue group-A gamma loads EARLY — latency hides under phase-1
    f32x4 gA[8][2];
    if constexpr (EPI == 1) {
#pragma unroll
        for (int i = 0; i < 8; ++i) {
            const int r = i * 8 + (l >> 3);
            const float* gp = &gamma[(size_t)(crow0 + r) * TT + ccol0 + (l & 7) * 8];
            gA[i][0] = *(const f32x4*)gp;
            gA[i][1] = *(const f32x4*)(gp + 4);
        }
    }

    // phase 1: acc (+bias) -> f16 into swizzled wave slice
#pragma unroll
    for (int m = 0; m < 8; ++m)
#pragma unroll
        for (int n = 0; n < 4; ++n) {
            float bsum = 0.f;
            if constexpr (EPI == 0) bsum = bias0[cb0 + n * 16 + fr];
#pragma unroll
            for (int j = 0; j < 4; ++j) {
                const int lr = m * 16 + rb + j;
                const int lcb = (n * 16 + fr) * 2;
                *(f16*)(slice + lr * 128 + (lcb ^ ((lr & 7) << 4))) = (f16)(acc[m][n][j] + bsum);
            }
        }
    asm volatile("s_waitcnt lgkmcnt(0)" ::: "memory");   // wave-internal writes visible
    __builtin_amdgcn_sched_barrier(0);                    // rule 18: pin reads after wait

    // phase 2: packed coalesced stores (16B/lane, 8x128B segments/inst)
    if constexpr (EPI == 1) {
        // issue group-B loads now (acc dead; they fly behind group-A consume)
        f32x4 gB[8][2];
#pragma unroll
        for (int i = 0; i < 8; ++i) {
            const int r = (8 + i) * 8 + (l >> 3);
            const float* gp = &gamma[(size_t)(crow0 + r) * TT + ccol0 + (l & 7) * 8];
            gB[i][0] = *(const f32x4*)gp;
            gB[i][1] = *(const f32x4*)(gp + 4);
        }
        // consume group A
#pragma unroll
        for (int i = 0; i < 8; ++i) {
            const int r  = i * 8 + (l >> 3);
            const int cb = (l & 7) * 16;
            f16x8 vv = *(const f16x8*)(slice + r * 128 + (cb ^ ((r & 7) << 4)));
            f16x8 o;
#pragma unroll
            for (int j = 0; j < 4; ++j) {
                o[j]     = (f16)((float)vv[j] * gA[i][0][j]);
                o[j + 4] = (f16)((float)vv[j + 4] * gA[i][1][j]);
            }
            *(f16x8*)&g_sg[(size_t)(crow0 + r) * TT + ccol0 + (l & 7) * 8] = o;
        }
        // consume group B
#pragma unroll
        for (int i = 0; i < 8; ++i) {
            const int r  = (8 + i) * 8 + (l >> 3);
            const int cb = (l & 7) * 16;
            f16x8 vv = *(const f16x8*)(slice + r * 128 + (cb ^ ((r & 7) << 4)));
            f16x8 o;
#pragma unroll
            for (int j = 0; j < 4; ++j) {
                o[j]     = (f16)((float)vv[j] * gB[i][0][j]);
                o[j + 4] = (f16)((float)vv[j + 4] * gB[i][1][j]);
            }
            *(f16x8*)&g_sg[(size_t)(crow0 + r) * TT + ccol0 + (l & 7) * 8] = o;
        }
    } else {
        f16* dst;
        int ld;
        if constexpr (EPI == 0) { dst = (sel == 0) ? g_q : (sel == 1) ? g_k : g_v; ld = 1024; }
        else                    { dst = g_part[blockIdx.z]; ld = 1024; }
#pragma unroll
        for (int i = 0; i < 16; ++i) {
            const int r  = i * 8 + (l >> 3);
            const int cb = (l & 7) * 16;
            f16x8 vv = *(const f16x8*)(slice + r * 128 + (cb ^ ((r & 7) << 4)));
            *(f16x8*)&dst[(size_t)(crow0 + r) * ld + cb0 + (l & 7) * 8] = vv;
        }
    }
}

// sum 4 split-K f16 partials -> g_ret f16
__global__ __launch_bounds__(256) void reduce_parts() {
    size_t i = (size_t)(blockIdx.x * 256 + threadIdx.x) * 8;
    f16x8 a = *(const f16x8*)&g_part[0][i];
    f16x8 b = *(const f16x8*)&g_part[1][i];
    f16x8 cc = *(const f16x8*)&g_part[2][i];
    f16x8 d = *(const f16x8*)&g_part[3][i];
    f16x8 o;
#pragma unroll
    for (int j = 0; j < 8; ++j)
        o[j] = (f16)((float)a[j] + (float)b[j] + (float)cc[j] + (float)d[j]);
    *(f16x8*)&g_ret[i] = o;
}

// sum 4 split-K f16 partials + bias + PReLU -> out f32
__global__ __launch_bounds__(256) void reduce_out(const float* __restrict__ br,
                                                  const float* __restrict__ prelu_a,
                                                  float* __restrict__ out) {
    size_t i = (size_t)(blockIdx.x * 256 + threadIdx.x) * 8;
    f16x8 a = *(const f16x8*)&g_part[0][i];
    f16x8 b = *(const f16x8*)&g_part[1][i];
    f16x8 cc = *(const f16x8*)&g_part[2][i];
    f16x8 d = *(const f16x8*)&g_part[3][i];
    const float pa = *prelu_a;
    const int col = (int)(i & 1023);
    const f32x4 b0 = *(const f32x4*)&br[col];
    const f32x4 b1 = *(const f32x4*)&br[col + 4];
    f32x4 o0, o1;
#pragma unroll
    for (int j = 0; j < 4; ++j) {
        float s = (float)a[j] + (float)b[j] + (float)cc[j] + (float)d[j] + b0[j];
        o0[j] = (s >= 0.f) ? s : pa * s;
    }
#pragma unroll
    for (int j = 0; j < 4; ++j) {
        float s = (float)a[j + 4] + (float)b[j + 4] + (float)cc[j + 4] + (float)d[j + 4] + b1[j];
        o1[j] = (s >= 0.f) ? s : pa * s;
    }
    *(f32x4*)&out[i] = o0;
    *(f32x4*)&out[i + 4] = o1;
}

extern "C" void kernel_launch(void* const* d_in, const int* in_sizes, int n_in,
                              void* d_out, int out_size, void* d_ws, size_t ws_size,
                              hipStream_t stream) {
    const float* x     = (const float*)d_in[0];
    const float* gamma = (const float*)d_in[1];
    const float* Wq    = (const float*)d_in[2];
    const float* bq    = (const float*)d_in[3];
    const float* Wk    = (const float*)d_in[4];
    const float* bk    = (const float*)d_in[5];
    const float* Wv    = (const float*)d_in[6];
    const float* bv    = (const float*)d_in[7];
    const float* Wr    = (const float*)d_in[8];
    const float* br    = (const float*)d_in[9];
    const float* pa    = (const float*)d_in[10];
    float* out = (float*)d_out;

    prep_cast_x<<<TT * DIN / 8 / 256, 256, 0, stream>>>(x);
    prep_transpose<<<dim3(16, 16, 4), 256, 0, stream>>>(Wq, Wk, Wv, Wr);

    // EPI 0: qkv  M=4096 N=3072  (192 blocks)
    gemm8<0><<<dim3(12, 16), 512, 0, stream>>>(gamma, bq, bk, bv);
    transpose_v<<<dim3(16, 64), 256, 0, stream>>>();
    // EPI 1: g_sg = gamma .* (q k^T)  M=4096 N=4096  (256 blocks)
    gemm8<1><<<dim3(16, 16), 512, 0, stream>>>(gamma, bq, bk, bv);
    // EPI 2: retained partials, split-K=4 over K=4096  (256 blocks)
    gemm8<2><<<dim3(4, 16, 4), 512, 0, stream>>>(gamma, bq, bk, bv);
    reduce_parts<<<TT * DIN / 8 / 256, 256, 0, stream>>>();
    // EPI 3: out partials, split-K=4 over K=1024 (NT=4)  (256 blocks)
    gemm8<3><<<dim3(4, 16, 4), 512, 0, stream>>>(gamma, bq, bk, bv);
    reduce_out<<<TT * DIN / 8 / 256, 256, 0, stream>>>(br, pa, out);
}